// Round 1
// baseline (111.117 us; speedup 1.0000x reference)
//
#include <hip/hip_runtime.h>
#include <math.h>

#define N     4096
#define BLOCK 256
#define JSPLIT (N / BLOCK)   // 16 j-segments, each exactly BLOCK wide

// sigmoid(t - dd) = 1 / (1 + e^{dd} * e^{-t});  e^{-t} for t in {0.5,1,2,4}:
#define EC1 0.60653065971f   // e^-0.5
#define EC2 0.36787944117f   // e^-1
#define EC3 0.13533528324f   // e^-2
#define EC4 0.01831563889f   // e^-4

__global__ void init_ws_kernel(float* ws, int nvals) {
    int t = threadIdx.x + blockIdx.x * blockDim.x;
    if (t < nvals) ws[t] = 0.0f;
}

__global__ __launch_bounds__(BLOCK) void lddt_main_kernel(
    const float* __restrict__ pred, const float* __restrict__ truec,
    const int* __restrict__ is_dna, const int* __restrict__ is_rna,
    const int* __restrict__ cmask, float* __restrict__ ws)
{
    const int jseg  = blockIdx.x;
    const int itile = blockIdx.y;
    const int batch = blockIdx.z;
    const int tid   = threadIdx.x;
    const int i     = itile * BLOCK + tid;

    const float* pb = pred  + (size_t)batch * N * 3;
    const float* tb = truec + (size_t)batch * N * 3;
    const int* dnab = is_dna + (size_t)batch * N;
    const int* rnab = is_rna + (size_t)batch * N;
    const int* cmb  = cmask  + (size_t)batch * N;

    __shared__ float jpx[BLOCK], jpy[BLOCK], jpz[BLOCK];
    __shared__ float jtx[BLOCK], jty[BLOCK], jtz[BLOCK];
    __shared__ float jnuc[BLOCK], jcm[BLOCK];

    const int j0 = jseg * BLOCK;
    {
        const int j = j0 + tid;
        jpx[tid] = pb[j * 3 + 0]; jpy[tid] = pb[j * 3 + 1]; jpz[tid] = pb[j * 3 + 2];
        jtx[tid] = tb[j * 3 + 0]; jty[tid] = tb[j * 3 + 1]; jtz[tid] = tb[j * 3 + 2];
        jnuc[tid] = (dnab[j] | rnab[j]) ? 1.0f : 0.0f;
        jcm[tid]  = cmb[j] ? 1.0f : 0.0f;
    }
    __syncthreads();

    const float pix = pb[i * 3 + 0], piy = pb[i * 3 + 1], piz = pb[i * 3 + 2];
    const float tix = tb[i * 3 + 0], tiy = tb[i * 3 + 1], tiz = tb[i * 3 + 2];
    const float inuc = (dnab[i] | rnab[i]) ? 1.0f : 0.0f;
    const float icm  = cmb[i] ? 1.0f : 0.0f;

    float num = 0.0f, den = 0.0f;

#pragma unroll 4
    for (int jj = 0; jj < BLOCK; ++jj) {
        // pred distance
        float dxp = pix - jpx[jj], dyp = piy - jpy[jj], dzp = piz - jpz[jj];
        float d2p = fmaf(dxp, dxp, fmaf(dyp, dyp, dzp * dzp));
        float dp  = __builtin_amdgcn_sqrtf(d2p);
        // true distance
        float dxt = tix - jtx[jj], dyt = tiy - jty[jj], dzt = tiz - jtz[jj];
        float d2t = fmaf(dxt, dxt, fmaf(dyt, dyt, dzt * dzt));
        float dt  = __builtin_amdgcn_sqrtf(d2t);

        float dd = fabsf(dt - dp);
        float e  = __expf(dd);   // v_exp_f32 path; dd >= 0 so e >= 1, overflow -> +inf -> sig -> 0 (correct)
        float s  = __builtin_amdgcn_rcpf(fmaf(e, EC1, 1.0f))
                 + __builtin_amdgcn_rcpf(fmaf(e, EC2, 1.0f))
                 + __builtin_amdgcn_rcpf(fmaf(e, EC3, 1.0f))
                 + __builtin_amdgcn_rcpf(fmaf(e, EC4, 1.0f));

        // cutoff: 30 if both nucleotide else 15
        float cutoff = (inuc * jnuc[jj] > 0.0f) ? 30.0f : 15.0f;
        float m = (dt < cutoff) ? 1.0f : 0.0f;
        m = (i == j0 + jj) ? 0.0f : m;     // exclude diagonal
        m *= icm * jcm[jj];                // paired coords mask

        den += m;
        num  = fmaf(m, 0.25f * s, num);
    }

    // wave (64-lane) shuffle reduction
    for (int off = 32; off > 0; off >>= 1) {
        num += __shfl_down(num, off);
        den += __shfl_down(den, off);
    }
    __shared__ float rnum[BLOCK / 64], rden[BLOCK / 64];
    const int wid = tid >> 6, lane = tid & 63;
    if (lane == 0) { rnum[wid] = num; rden[wid] = den; }
    __syncthreads();
    if (tid == 0) {
        float tn = 0.0f, td = 0.0f;
        for (int w = 0; w < BLOCK / 64; ++w) { tn += rnum[w]; td += rden[w]; }
        atomicAdd(&ws[batch * 2 + 0], tn);
        atomicAdd(&ws[batch * 2 + 1], td);
    }
}

__global__ void finalize_kernel(const float* __restrict__ ws, float* __restrict__ out, int b) {
    float acc = 0.0f;
    for (int k = 0; k < b; ++k) {
        float nm = ws[2 * k + 0];
        float dn = ws[2 * k + 1];
        acc += nm / fmaxf(dn, 1.0f);
    }
    out[0] = 1.0f - acc / (float)b;
}

extern "C" void kernel_launch(void* const* d_in, const int* in_sizes, int n_in,
                              void* d_out, int out_size, void* d_ws, size_t ws_size,
                              hipStream_t stream) {
    const float* pred  = (const float*)d_in[0];
    const float* truec = (const float*)d_in[1];
    const int* is_dna  = (const int*)d_in[2];
    const int* is_rna  = (const int*)d_in[3];
    const int* cmask   = (const int*)d_in[4];
    float* out = (float*)d_out;
    float* ws  = (float*)d_ws;

    const int b = in_sizes[2] / N;   // is_dna has b*n elements

    init_ws_kernel<<<1, 64, 0, stream>>>(ws, 2 * b);

    dim3 grid(JSPLIT, N / BLOCK, b);
    lddt_main_kernel<<<grid, BLOCK, 0, stream>>>(pred, truec, is_dna, is_rna, cmask, ws);

    finalize_kernel<<<1, 1, 0, stream>>>(ws, out, b);
}

// Round 2
// 91.881 us; speedup vs baseline: 1.2094x; 1.2094x over previous
//
#include <hip/hip_runtime.h>
#include <math.h>

#define N      4096
#define BLOCK  256
#define SEG    64
#define NJSEG  (N / SEG)      // 64 j-segments
#define NITILE (N / BLOCK)    // 16 i-tiles
#define NBLK   (NJSEG * NITILE)  // 1024 blocks per batch

// s(e) = sum_k 1/(1 + c_k*e), c_k = e^{-t_k}, t = {0.5,1,2,4}
//      = N(e)/D(e);  coeff of e^m in N = (4-m)*S_m, D = 1 + S1 e + S2 e^2 + S3 e^3 + S4 e^4
// S1..S4 = elementary symmetric polynomials of {e^-.5, e^-1, e^-2, e^-4}
#define PN0 4.0f
#define PN1 3.384183069f
#define PN2 0.750655861f
#define PN3 0.036699475f
#define PD1 1.128061023f
#define PD2 0.375327930f
#define PD3 0.036699475f
#define PD4 0.000553084f
#define S_AT_ZERO 3.2163286f   // N(1)/D(1) = sum_k sigmoid(t_k)

__global__ __launch_bounds__(BLOCK, 6) void lddt_main_kernel(
    const float* __restrict__ pred, const float* __restrict__ truec,
    const int* __restrict__ is_dna, const int* __restrict__ is_rna,
    const int* __restrict__ cmask, float* __restrict__ ws)
{
    const int jseg  = blockIdx.x;   // 0..63
    const int itile = blockIdx.y;   // 0..15
    const int batch = blockIdx.z;
    const int tid   = threadIdx.x;
    const int i     = itile * BLOCK + tid;

    const float* pb = pred  + (size_t)batch * N * 3;
    const float* tb = truec + (size_t)batch * N * 3;
    const int* dnab = is_dna + (size_t)batch * N;
    const int* rnab = is_rna + (size_t)batch * N;
    const int* cmb  = cmask  + (size_t)batch * N;

    // jP = {px,py,pz, nuc?15:0}, jT = {tx,ty,tz, cm?1:0}
    __shared__ float4 jP[SEG], jT[SEG];
    const int j0 = jseg * SEG;
    if (tid < SEG) {
        const int j = j0 + tid;
        jP[tid] = make_float4(pb[j*3+0], pb[j*3+1], pb[j*3+2],
                              (dnab[j] | rnab[j]) ? 15.0f : 0.0f);
        jT[tid] = make_float4(tb[j*3+0], tb[j*3+1], tb[j*3+2],
                              cmb[j] ? 1.0f : 0.0f);
    }
    __syncthreads();

    const float pix = pb[i*3+0], piy = pb[i*3+1], piz = pb[i*3+2];
    const float tix = tb[i*3+0], tiy = tb[i*3+1], tiz = tb[i*3+2];
    const float inuc01 = (dnab[i] | rnab[i]) ? 1.0f : 0.0f;
    const float icm    = cmb[i] ? 1.0f : 0.0f;

    float num = 0.0f, den = 0.0f;

#pragma unroll 8
    for (int jj = 0; jj < SEG; ++jj) {
        const float4 P = jP[jj];
        const float4 T = jT[jj];

        float dxp = pix - P.x, dyp = piy - P.y, dzp = piz - P.z;
        float d2p = fmaf(dxp, dxp, fmaf(dyp, dyp, dzp * dzp));
        float dp  = __builtin_amdgcn_sqrtf(d2p);

        float dxt = tix - T.x, dyt = tiy - T.y, dzt = tiz - T.z;
        float d2t = fmaf(dxt, dxt, fmaf(dyt, dyt, dzt * dzt));
        float dt  = __builtin_amdgcn_sqrtf(d2t);

        // clamp avoids e^4 overflow -> inf/inf; s(20) ~ 1e-7, negligible
        float dd = fminf(fabsf(dt - dp), 20.0f);
        float e  = __expf(dd);

        float nN = fmaf(e, fmaf(e, fmaf(e, PN3, PN2), PN1), PN0);
        float nD = fmaf(e, fmaf(e, fmaf(e, fmaf(e, PD4, PD3), PD2), PD1), 1.0f);
        float s  = nN * __builtin_amdgcn_rcpf(nD);

        float cutoff = fmaf(inuc01, P.w, 15.0f);   // 30 if both nucleotide else 15
        float m = (dt < cutoff) ? T.w : 0.0f;      // cm_j folded into the select
        den += m;
        num  = fmaf(m, s, num);
    }

    // closed-form diagonal removal: the block containing j==i contributed
    // m=cm_i, s=S_AT_ZERO exactly once (at dt=dp=0)
    if ((i >> 6) == jseg) {
        num = fmaf(-S_AT_ZERO, icm, num);
        den -= icm;
    }
    num *= 0.25f * icm;   // threshold-mean + cm_i factored out of the loop
    den *= icm;

    // wave (64) shuffle reduce, then cross-wave via LDS
    for (int off = 32; off > 0; off >>= 1) {
        num += __shfl_down(num, off);
        den += __shfl_down(den, off);
    }
    __shared__ float rn[BLOCK / 64], rd[BLOCK / 64];
    const int wid = tid >> 6, lane = tid & 63;
    if (lane == 0) { rn[wid] = num; rd[wid] = den; }
    __syncthreads();
    if (tid == 0) {
        float tn = rn[0] + rn[1] + rn[2] + rn[3];
        float td = rd[0] + rd[1] + rd[2] + rd[3];
        const int bid = (batch * NITILE + itile) * NJSEG + jseg;
        ws[bid * 2 + 0] = tn;   // unconditional write -> no init kernel needed
        ws[bid * 2 + 1] = td;
    }
}

__global__ __launch_bounds__(BLOCK) void finalize_kernel(
    const float* __restrict__ ws, float* __restrict__ out, int b)
{
    __shared__ float sn[4], sd[4];
    float acc = 0.0f;
    for (int k = 0; k < b; ++k) {
        float n = 0.0f, d = 0.0f;
        for (int p = threadIdx.x; p < NBLK; p += BLOCK) {
            n += ws[(k * NBLK + p) * 2 + 0];
            d += ws[(k * NBLK + p) * 2 + 1];
        }
        for (int off = 32; off > 0; off >>= 1) {
            n += __shfl_down(n, off);
            d += __shfl_down(d, off);
        }
        if ((threadIdx.x & 63) == 0) { sn[threadIdx.x >> 6] = n; sd[threadIdx.x >> 6] = d; }
        __syncthreads();
        if (threadIdx.x == 0) {
            float tn = sn[0] + sn[1] + sn[2] + sn[3];
            float td = sd[0] + sd[1] + sd[2] + sd[3];
            acc += tn / fmaxf(td, 1.0f);
        }
        __syncthreads();
    }
    if (threadIdx.x == 0) out[0] = 1.0f - acc / (float)b;
}

extern "C" void kernel_launch(void* const* d_in, const int* in_sizes, int n_in,
                              void* d_out, int out_size, void* d_ws, size_t ws_size,
                              hipStream_t stream) {
    const float* pred  = (const float*)d_in[0];
    const float* truec = (const float*)d_in[1];
    const int* is_dna  = (const int*)d_in[2];
    const int* is_rna  = (const int*)d_in[3];
    const int* cmask   = (const int*)d_in[4];
    float* out = (float*)d_out;
    float* ws  = (float*)d_ws;

    const int b = in_sizes[2] / N;

    dim3 grid(NJSEG, NITILE, b);   // 64 x 16 x b = 2048 blocks for b=2
    lddt_main_kernel<<<grid, BLOCK, 0, stream>>>(pred, truec, is_dna, is_rna, cmask, ws);
    finalize_kernel<<<1, BLOCK, 0, stream>>>(ws, out, b);
}

// Round 3
// 86.631 us; speedup vs baseline: 1.2826x; 1.0606x over previous
//
#include <hip/hip_runtime.h>
#include <math.h>

#define N      4096
#define BLOCK  256
#define SEG    64
#define NITILE (N / BLOCK)            // 16 i-tiles
#define NJSEG  (N / SEG)              // 64 j-segments
// upper-triangle tiles: for itile t, jseg runs 4t..63 -> 64-4t blocks
// offset(t) = 66t - 2t^2 ; total = offset(16) = 544
#define NTILE_TRI 544

// s(e) = sum_k 1/(1 + c_k*e), c_k = e^{-t_k}, t = {0.5,1,2,4} = N(e)/D(e)
#define PN0 4.0f
#define PN1 3.384183069f
#define PN2 0.750655861f
#define PN3 0.036699475f
#define PD1 1.128061023f
#define PD2 0.375327930f
#define PD3 0.036699475f
#define PD4 0.000553084f

__device__ __forceinline__ int tri_offset(int t) { return 66 * t - 2 * t * t; }

__global__ __launch_bounds__(BLOCK, 6) void lddt_main_kernel(
    const float* __restrict__ pred, const float* __restrict__ truec,
    const int* __restrict__ is_dna, const int* __restrict__ is_rna,
    const int* __restrict__ cmask, float* __restrict__ ws)
{
    const int L     = blockIdx.x;     // 0..543, linear upper-tri tile id
    const int batch = blockIdx.z;
    const int tid   = threadIdx.x;

    // decode (itile, jseg) from L  (uniform scalar work)
    int itile = 0;
#pragma unroll
    for (int u = 1; u < NITILE; ++u) itile += (L >= tri_offset(u)) ? 1 : 0;
    const int jseg = 4 * itile + (L - tri_offset(itile));
    const bool diag = (jseg >> 2) == itile;   // tile straddles the diagonal

    const int i = itile * BLOCK + tid;

    const float* pb = pred  + (size_t)batch * N * 3;
    const float* tb = truec + (size_t)batch * N * 3;
    const int* dnab = is_dna + (size_t)batch * N;
    const int* rnab = is_rna + (size_t)batch * N;
    const int* cmb  = cmask  + (size_t)batch * N;

    // jP = {px,py,pz, nuc?15:0}, jT = {tx,ty,tz, cm?1:0}
    __shared__ float4 jP[SEG], jT[SEG];
    const int j0 = jseg * SEG;
    if (tid < SEG) {
        const int j = j0 + tid;
        jP[tid] = make_float4(pb[j*3+0], pb[j*3+1], pb[j*3+2],
                              (dnab[j] | rnab[j]) ? 15.0f : 0.0f);
        jT[tid] = make_float4(tb[j*3+0], tb[j*3+1], tb[j*3+2],
                              cmb[j] ? 1.0f : 0.0f);
    }
    __syncthreads();

    const float pix = pb[i*3+0], piy = pb[i*3+1], piz = pb[i*3+2];
    const float tix = tb[i*3+0], tiy = tb[i*3+1], tiz = tb[i*3+2];
    const float inuc01 = (dnab[i] | rnab[i]) ? 1.0f : 0.0f;
    const float icm    = cmb[i] ? 1.0f : 0.0f;

    float num = 0.0f, den = 0.0f;

#define PAIR_BODY(JJ, NEED_TRI)                                                \
    {                                                                          \
        const float4 P = jP[JJ];                                               \
        const float4 T = jT[JJ];                                               \
        float dxp = pix - P.x, dyp = piy - P.y, dzp = piz - P.z;               \
        float d2p = fmaf(dxp, dxp, fmaf(dyp, dyp, dzp * dzp));                 \
        float dp  = __builtin_amdgcn_sqrtf(d2p);                               \
        float dxt = tix - T.x, dyt = tiy - T.y, dzt = tiz - T.z;               \
        float d2t = fmaf(dxt, dxt, fmaf(dyt, dyt, dzt * dzt));                 \
        float dt  = __builtin_amdgcn_sqrtf(d2t);                               \
        float dd = fminf(fabsf(dt - dp), 20.0f);                               \
        float e  = __expf(dd);                                                 \
        float nN = fmaf(e, fmaf(e, fmaf(e, PN3, PN2), PN1), PN0);              \
        float nD = fmaf(e, fmaf(e, fmaf(e, fmaf(e, PD4, PD3), PD2), PD1), 1.0f);\
        float s  = nN * __builtin_amdgcn_rcpf(nD);                             \
        float cutoff = fmaf(inuc01, P.w, 15.0f);                               \
        bool keep = (dt < cutoff);                                             \
        if (NEED_TRI) keep = keep && (j0 + (JJ) > i);                          \
        float m = keep ? T.w : 0.0f;                                           \
        den += m;                                                              \
        num  = fmaf(m, s, num);                                                \
    }

    if (diag) {
#pragma unroll 8
        for (int jj = 0; jj < SEG; ++jj) PAIR_BODY(jj, true)
    } else {
#pragma unroll 8
        for (int jj = 0; jj < SEG; ++jj) PAIR_BODY(jj, false)
    }
#undef PAIR_BODY

    // each kept pair (i<j) counts for (i,j) and (j,i):  x2; threshold mean: /4
    num *= 0.5f * icm;
    den *= 2.0f * icm;

    for (int off = 32; off > 0; off >>= 1) {
        num += __shfl_down(num, off);
        den += __shfl_down(den, off);
    }
    __shared__ float rn[BLOCK / 64], rd[BLOCK / 64];
    const int wid = tid >> 6, lane = tid & 63;
    if (lane == 0) { rn[wid] = num; rd[wid] = den; }
    __syncthreads();
    if (tid == 0) {
        float tn = rn[0] + rn[1] + rn[2] + rn[3];
        float td = rd[0] + rd[1] + rd[2] + rd[3];
        const int bid = batch * NTILE_TRI + L;
        ws[bid * 2 + 0] = tn;   // unconditional write -> no init kernel needed
        ws[bid * 2 + 1] = td;
    }
}

__global__ __launch_bounds__(BLOCK) void finalize_kernel(
    const float* __restrict__ ws, float* __restrict__ out, int b)
{
    __shared__ float sn[4], sd[4];
    float acc = 0.0f;
    for (int k = 0; k < b; ++k) {
        float n = 0.0f, d = 0.0f;
        for (int p = threadIdx.x; p < NTILE_TRI; p += BLOCK) {
            n += ws[(k * NTILE_TRI + p) * 2 + 0];
            d += ws[(k * NTILE_TRI + p) * 2 + 1];
        }
        for (int off = 32; off > 0; off >>= 1) {
            n += __shfl_down(n, off);
            d += __shfl_down(d, off);
        }
        if ((threadIdx.x & 63) == 0) { sn[threadIdx.x >> 6] = n; sd[threadIdx.x >> 6] = d; }
        __syncthreads();
        if (threadIdx.x == 0) {
            float tn = sn[0] + sn[1] + sn[2] + sn[3];
            float td = sd[0] + sd[1] + sd[2] + sd[3];
            acc += tn / fmaxf(td, 1.0f);
        }
        __syncthreads();
    }
    if (threadIdx.x == 0) out[0] = 1.0f - acc / (float)b;
}

extern "C" void kernel_launch(void* const* d_in, const int* in_sizes, int n_in,
                              void* d_out, int out_size, void* d_ws, size_t ws_size,
                              hipStream_t stream) {
    const float* pred  = (const float*)d_in[0];
    const float* truec = (const float*)d_in[1];
    const int* is_dna  = (const int*)d_in[2];
    const int* is_rna  = (const int*)d_in[3];
    const int* cmask   = (const int*)d_in[4];
    float* out = (float*)d_out;
    float* ws  = (float*)d_ws;

    const int b = in_sizes[2] / N;

    dim3 grid(NTILE_TRI, 1, b);   // 544 upper-triangle tiles per batch
    lddt_main_kernel<<<grid, BLOCK, 0, stream>>>(pred, truec, is_dna, is_rna, cmask, ws);
    finalize_kernel<<<1, BLOCK, 0, stream>>>(ws, out, b);
}